// Round 8
// baseline (202.572 us; speedup 1.0000x reference)
//
#include <hip/hip_runtime.h>

#define Bb 4
#define Nn 2048
#define Dd 1024
#define Rr 64
#define LN_EPS 1e-5f

typedef unsigned short u16;
typedef short bf16x8 __attribute__((ext_vector_type(8)));   // 8 bf16 in 4 VGPRs
typedef float f32x4 __attribute__((ext_vector_type(4)));

__device__ __forceinline__ u16 f2bf(float f) {
  unsigned u = __float_as_uint(f);
  u += 0x7FFFu + ((u >> 16) & 1u);   // RNE
  return (u16)(u >> 16);
}

// async global->LDS, 16 B per lane. LDS dest is wave-uniform base + lane*16.
__device__ __forceinline__ void g2l16(u16* l, const u16* g) {
  __builtin_amdgcn_global_load_lds(
      (const __attribute__((address_space(1))) unsigned int*)g,
      (__attribute__((address_space(3))) unsigned int*)l, 16, 0, 0);
}

// ---- prep_x: x (B,N,D) f32 -> xt (B,D,N) bf16 (d-major, pv_gemm B-operand) ----
__global__ __launch_bounds__(256) void prep_x(const float* __restrict__ x,
                                              u16* __restrict__ xt) {
  __shared__ float tile[64][65];
  const int b = blockIdx.z;
  const int n0 = blockIdx.x * 64;
  const int d0 = blockIdx.y * 64;
  const int t = threadIdx.x;
  const int c = t & 63, r4 = t >> 6;
#pragma unroll
  for (int rr = 0; rr < 16; rr++) {
    int row = rr * 4 + r4;
    tile[row][c] = x[(size_t)(b * Nn + n0 + row) * Dd + d0 + c];
  }
  __syncthreads();
#pragma unroll
  for (int rr = 0; rr < 16; rr++) {
    int dd = rr * 4 + r4;
    xt[(size_t)(b * Dd + d0 + dd) * Nn + n0 + c] = f2bf(tile[c][dd]);
  }
}

// ---- prep_uv: U,V (D,R) f32 -> uvt (128,D) bf16 (R7: qs moved into proj_qk) ----
__global__ __launch_bounds__(256) void prep_uv(const float* __restrict__ U,
    const float* __restrict__ V, u16* __restrict__ uvt) {
  __shared__ float tile[64][65];
  const int which = blockIdx.x >> 4;
  const int d0 = (blockIdx.x & 15) * 64;
  const float* src = which ? V : U;
  const int t = threadIdx.x, c = t & 63, r4 = t >> 6;
#pragma unroll
  for (int rr = 0; rr < 16; rr++) {
    int row = rr * 4 + r4;
    tile[row][c] = src[(size_t)(d0 + row) * Rr + c];
  }
  __syncthreads();
#pragma unroll
  for (int rr = 0; rr < 16; rr++) {
    int r = rr * 4 + r4;
    uvt[(size_t)(which * 64 + r) * Dd + d0 + c] = f2bf(tile[c][r]);
  }
}

// ---- proj_qk: Q = (x@U)*mask*qs[row], K = (x@V)*mask.
// R7: 16 rows x 128 cols/block, grid 512 (2 blocks/CU — R6's 256-block version
// was 1 block/CU latency-bound). A/B loads double-buffered one k-step ahead.
// qs = 1/sqrt(max(sum mask_row,1)) computed inline (qscale kernel removed).
__global__ __launch_bounds__(256) void proj_qk(const float* __restrict__ x,
    const float* __restrict__ mask, const u16* __restrict__ uvt,
    u16* __restrict__ Qo, u16* __restrict__ Ko) {
  __shared__ float qsl[16];
  const int t = threadIdx.x;
  const int w = t >> 6, l = t & 63, quad = l >> 4, l16 = l & 15;
  const int g0 = blockIdx.x * 16;
  // qs for the block's 16 rows: wave w handles rows {it*4+w}
#pragma unroll
  for (int it = 0; it < 4; it++) {
    const int row = it * 4 + w;
    float v = mask[(size_t)(g0 + row) * Rr + l];
#pragma unroll
    for (int off = 32; off; off >>= 1) v += __shfl_xor(v, off);
    if (l == 0) qsl[row] = rsqrtf(fmaxf(v, 1.0f));
  }
  f32x4 acc[2];
  acc[0] = (f32x4){0.f, 0.f, 0.f, 0.f};
  acc[1] = (f32x4){0.f, 0.f, 0.f, 0.f};
  // double-buffered K-loop
  bf16x8 a_cur, b_cur[2];
  {
    const float4* px = (const float4*)&x[(size_t)(g0 + l16) * Dd + quad * 8];
    float4 x0 = px[0], x1 = px[1];
    a_cur[0] = (short)f2bf(x0.x); a_cur[1] = (short)f2bf(x0.y);
    a_cur[2] = (short)f2bf(x0.z); a_cur[3] = (short)f2bf(x0.w);
    a_cur[4] = (short)f2bf(x1.x); a_cur[5] = (short)f2bf(x1.y);
    a_cur[6] = (short)f2bf(x1.z); a_cur[7] = (short)f2bf(x1.w);
#pragma unroll
    for (int i = 0; i < 2; i++) {
      int col = w * 32 + i * 16 + l16;
      b_cur[i] = *(const bf16x8*)&uvt[(size_t)col * Dd + quad * 8];
    }
  }
  for (int k0 = 0; k0 < Dd; k0 += 32) {
    const int k1 = (k0 + 32 < Dd) ? k0 + 32 : 0;
    bf16x8 a_nxt, b_nxt[2];
    {
      const float4* px = (const float4*)&x[(size_t)(g0 + l16) * Dd + k1 + quad * 8];
      float4 x0 = px[0], x1 = px[1];
      a_nxt[0] = (short)f2bf(x0.x); a_nxt[1] = (short)f2bf(x0.y);
      a_nxt[2] = (short)f2bf(x0.z); a_nxt[3] = (short)f2bf(x0.w);
      a_nxt[4] = (short)f2bf(x1.x); a_nxt[5] = (short)f2bf(x1.y);
      a_nxt[6] = (short)f2bf(x1.z); a_nxt[7] = (short)f2bf(x1.w);
#pragma unroll
      for (int i = 0; i < 2; i++) {
        int col = w * 32 + i * 16 + l16;
        b_nxt[i] = *(const bf16x8*)&uvt[(size_t)col * Dd + k1 + quad * 8];
      }
    }
#pragma unroll
    for (int i = 0; i < 2; i++)
      acc[i] = __builtin_amdgcn_mfma_f32_16x16x32_bf16(a_cur, b_cur[i], acc[i], 0, 0, 0);
    a_cur = a_nxt; b_cur[0] = b_nxt[0]; b_cur[1] = b_nxt[1];
  }
  __syncthreads();   // qsl ready for all waves
#pragma unroll
  for (int i = 0; i < 2; i++) {
    const int col = w * 32 + i * 16 + l16;
    const int r_ = col & 63;
#pragma unroll
    for (int r = 0; r < 4; r++) {
      const int rl = quad * 4 + r;
      const int row = g0 + rl;
      float v = acc[i][r] * mask[(size_t)row * Rr + r_];
      if (col < 64) Qo[(size_t)row * Rr + r_] = f2bf(v * qsl[rl]);
      else          Ko[(size_t)row * Rr + r_] = f2bf(v);
    }
  }
}

// ---- score_softmax: R7: block = 16 q-rows x ALL 2048 keys, 8 waves, grid 512.
// acc halves to 64 VGPR -> launch_bounds(512,4) -> 2 blocks/CU (R6's 32-row
// version was 1 block/CU at 128 acc VGPRs). Whole-row softmax once per block.
// Writes P = exp(v - rowmax) bf16 (unnormalized, Q pre-scaled by qs) + linv.
// Slab stride 72 u16 (144 B, 16 B-aligned): quad-rows (stride 4) land on
// different banks (4*36 mod 32 = 16), killing R6's 4-way write conflict.
__global__ __launch_bounds__(512, 4) void score_softmax(
    const u16* __restrict__ Qm, const u16* __restrict__ Km,
    u16* __restrict__ Pw, float* __restrict__ linv_g) {
  __shared__ float red[16][8];
  __shared__ float mfin[16];
  __shared__ u16 tsl[8][16][72];   // per-wave transpose slab (18 KB)
  const int t = threadIdx.x;
  const int w = t >> 6, l = t & 63, quad = l >> 4, l16 = l & 15;
  const int id = blockIdx.x;
  const int xcd = id & 7;
  const int b = xcd >> 1;
  const int q0 = (((id >> 3) << 1) | (xcd & 1)) * 16;
  bf16x8 qf[2];
#pragma unroll
  for (int ks = 0; ks < 2; ks++)
    qf[ks] = *(const bf16x8*)&Qm[(size_t)(b * Nn + q0 + l16) * Rr + ks * 32 + quad * 8];
  f32x4 acc[16];
#pragma unroll
  for (int nt = 0; nt < 16; nt++) acc[nt] = (f32x4){0.f, 0.f, 0.f, 0.f};
#pragma unroll
  for (int nt = 0; nt < 16; nt++) {
#pragma unroll
    for (int ks = 0; ks < 2; ks++) {
      bf16x8 kf = *(const bf16x8*)&Km[(size_t)(b * Nn + w * 256 + nt * 16 + l16) * Rr + ks * 32 + quad * 8];
      acc[nt] = __builtin_amdgcn_mfma_f32_16x16x32_bf16(qf[ks], kf, acc[nt], 0, 0, 0);
    }
  }
  // ---- row max: in-reg over nt, shuffle over l16 (within quad), LDS over waves ----
  float vmax[4];
#pragma unroll
  for (int r = 0; r < 4; r++) {
    float m = -1e30f;
#pragma unroll
    for (int nt = 0; nt < 16; nt++) m = fmaxf(m, acc[nt][r]);
#pragma unroll
    for (int off = 1; off < 16; off <<= 1) m = fmaxf(m, __shfl_xor(m, off));
    vmax[r] = m;
  }
  if (l16 == 0) {
#pragma unroll
    for (int r = 0; r < 4; r++) red[quad * 4 + r][w] = vmax[r];
  }
  __syncthreads();
  if (t < 16) {
    float m = -1e30f;
#pragma unroll
    for (int i = 0; i < 8; i++) m = fmaxf(m, red[t][i]);
    mfin[t] = m;
  }
  __syncthreads();
  // ---- exp + row sum ----
  float rowm[4], vsum[4];
#pragma unroll
  for (int r = 0; r < 4; r++) { rowm[r] = mfin[quad * 4 + r]; vsum[r] = 0.f; }
#pragma unroll
  for (int nt = 0; nt < 16; nt++)
#pragma unroll
    for (int r = 0; r < 4; r++) {
      float p = __expf(acc[nt][r] - rowm[r]);
      acc[nt][r] = p;
      vsum[r] += p;
    }
#pragma unroll
  for (int r = 0; r < 4; r++) {
#pragma unroll
    for (int off = 1; off < 16; off <<= 1) vsum[r] += __shfl_xor(vsum[r], off);
  }
  if (l16 == 0) {
#pragma unroll
    for (int r = 0; r < 4; r++) red[quad * 4 + r][w] = vsum[r];
  }
  __syncthreads();
  if (t < 16) {
    float s = 0.f;
#pragma unroll
    for (int i = 0; i < 8; i++) s += red[t][i];
    linv_g[(size_t)b * Nn + q0 + t] = 1.f / s;
  }
  // ---- write P coalesced via per-wave LDS transpose (64-col chunks) ----
#pragma unroll
  for (int c = 0; c < 4; c++) {
#pragma unroll
    for (int i = 0; i < 4; i++) {
      const int nt = c * 4 + i;
#pragma unroll
      for (int r = 0; r < 4; r++)
        tsl[w][quad * 4 + r][i * 16 + l16] = f2bf(acc[nt][r]);
    }
    // same-wave RAW through LDS: compiler inserts lgkmcnt waits
#pragma unroll
    for (int it = 0; it < 2; it++) {
      const int u = it * 64 + l;
      const int row = u >> 3, cg = u & 7;
      bf16x8 vv = *(const bf16x8*)&tsl[w][row][cg * 8];
      *(bf16x8*)&Pw[((size_t)(b * Nn + q0 + row)) * Nn + w * 256 + c * 64 + cg * 8] = vv;
    }
  }
}

// ---- pv_gemm: delta = P @ X, m97-recipe GEMM. 128x128 tile, BK=64.
// R5: XOR-swizzled LDS k-chunks (conflicts 1.26e7 -> 0, 64 -> 45.5 us).
__global__ __launch_bounds__(256, 2) void pv_gemm(
    const u16* __restrict__ Pw, const u16* __restrict__ xt,
    const float* __restrict__ x, const float* __restrict__ linv_g,
    float* __restrict__ y) {
  __shared__ u16 As[128 * 64];   // [row m][k-slot] swizzled
  __shared__ u16 Bs[128 * 64];   // [col n(d)][k-slot] swizzled
  const int t = threadIdx.x;
  const int w = t >> 6, l = t & 63, quad = l >> 4, l16 = l & 15;
  const int id = blockIdx.x;
  const int xcd = id & 7;
  const int b = xcd >> 1;
  const int nh = xcd & 1;
  const int rest = id >> 3;             // 0..63
  const int m0 = (rest & 15) * 128;     // 16 m-tiles
  const int n0 = (nh * 4 + (rest >> 4)) * 128;  // 8 n-tiles
  const int srow = w * 32 + (l >> 3);   // staging row base (per call +8)
  const int skoff = (((l & 7) ^ ((l >> 3) & 7)) * 8);  // swizzled global k-chunk
  f32x4 acc[4][4];
#pragma unroll
  for (int i = 0; i < 4; i++)
#pragma unroll
    for (int j = 0; j < 4; j++) acc[i][j] = (f32x4){0.f, 0.f, 0.f, 0.f};
  const int wm = w & 1, wn = w >> 1;
  const int sw = (l16 & 7);
  for (int k0 = 0; k0 < Nn; k0 += 64) {
    __syncthreads();   // previous compute done before LDS overwrite
#pragma unroll
    for (int c = 0; c < 4; c++) {
      int row = srow + c * 8;
      g2l16(&As[(w * 32 + c * 8) * 64],
            &Pw[((size_t)(b * Nn + m0 + row)) * Nn + k0 + skoff]);
      g2l16(&Bs[(w * 32 + c * 8) * 64],
            &xt[((size_t)(b * Dd + n0 + row)) * Nn + k0 + skoff]);
    }
    __syncthreads();   // drains vmcnt(0) then barrier
#pragma unroll
    for (int ks = 0; ks < 2; ks++) {
      const int slot = ((ks * 4 + quad) ^ sw) * 8;
      bf16x8 af[4], bf_[4];
#pragma unroll
      for (int mt = 0; mt < 4; mt++)
        af[mt] = *(const bf16x8*)&As[(wm * 64 + mt * 16 + l16) * 64 + slot];
#pragma unroll
      for (int nt = 0; nt < 4; nt++)
        bf_[nt] = *(const bf16x8*)&Bs[(wn * 64 + nt * 16 + l16) * 64 + slot];
#pragma unroll
      for (int mt = 0; mt < 4; mt++)
#pragma unroll
        for (int nt = 0; nt < 4; nt++)
          acc[mt][nt] = __builtin_amdgcn_mfma_f32_16x16x32_bf16(af[mt], bf_[nt], acc[mt][nt], 0, 0, 0);
    }
  }
  // ---- epilogue: y = x + linv[m] * delta ----
  float li[4][4];
#pragma unroll
  for (int mt = 0; mt < 4; mt++)
#pragma unroll
    for (int r = 0; r < 4; r++)
      li[mt][r] = linv_g[(size_t)b * Nn + m0 + wm * 64 + mt * 16 + quad * 4 + r];
#pragma unroll
  for (int mt = 0; mt < 4; mt++)
#pragma unroll
    for (int nt = 0; nt < 4; nt++) {
      const int nn = n0 + wn * 64 + nt * 16 + l16;
#pragma unroll
      for (int r = 0; r < 4; r++) {
        const int m = m0 + wm * 64 + mt * 16 + quad * 4 + r;
        const size_t off = ((size_t)(b * Nn + m)) * Dd + nn;
        y[off] = x[off] + li[mt][r] * acc[mt][nt][r];
      }
    }
}

// ---- ln_k: in-place row-wise LayerNorm. R7: one wave per row (4 rows/block,
// grid 2048) — zero barriers, zero LDS, shuffle-only reduction, full occupancy.
__global__ __launch_bounds__(256) void ln_k(float* __restrict__ y,
    const float* __restrict__ gamma, const float* __restrict__ beta) {
  const int t = threadIdx.x, w = t >> 6, lane = t & 63;
  const int row = blockIdx.x * 4 + w;
  float* p = y + (size_t)row * Dd;
  float4 v[4];
  float s = 0.f, q = 0.f;
#pragma unroll
  for (int i = 0; i < 4; i++) {
    v[i] = ((const float4*)p)[i * 64 + lane];
    s += v[i].x + v[i].y + v[i].z + v[i].w;
    q += v[i].x * v[i].x + v[i].y * v[i].y + v[i].z * v[i].z + v[i].w * v[i].w;
  }
#pragma unroll
  for (int off = 32; off; off >>= 1) {
    s += __shfl_xor(s, off);
    q += __shfl_xor(q, off);
  }
  const float mu = s * (1.f / Dd);
  const float var = q * (1.f / Dd) - mu * mu;
  const float rstd = rsqrtf(var + LN_EPS);
#pragma unroll
  for (int i = 0; i < 4; i++) {
    float4 g = ((const float4*)gamma)[i * 64 + lane];
    float4 be = ((const float4*)beta)[i * 64 + lane];
    float4 o;
    o.x = (v[i].x - mu) * rstd * g.x + be.x;
    o.y = (v[i].y - mu) * rstd * g.y + be.y;
    o.z = (v[i].z - mu) * rstd * g.z + be.z;
    o.w = (v[i].w - mu) * rstd * g.w + be.w;
    ((float4*)p)[i * 64 + lane] = o;
  }
}

extern "C" void kernel_launch(void* const* d_in, const int* in_sizes, int n_in,
                              void* d_out, int out_size, void* d_ws, size_t ws_size,
                              hipStream_t stream) {
  const float* x     = (const float*)d_in[0];
  const float* mask  = (const float*)d_in[1];
  const float* U     = (const float*)d_in[2];
  const float* V     = (const float*)d_in[3];
  const float* gamma = (const float*)d_in[4];
  const float* beta  = (const float*)d_in[5];
  float* out = (float*)d_out;
  char* ws = (char*)d_ws;
  // workspace layout (51 MB total)
  u16*   xt   = (u16*)ws;                                        // 16 MB (B,D,N) bf16
  u16*   Qw   = (u16*)(ws + (size_t)(16 << 20));                 // 1 MB
  u16*   Kw   = (u16*)(ws + (size_t)(17 << 20));                 // 1 MB
  u16*   uvt  = (u16*)(ws + (size_t)(18 << 20));                 // 256 KB
  float* linv = (float*)(ws + (size_t)(18 << 20) + (288 << 10)); // 32 KB
  u16*   Pw   = (u16*)(ws + (size_t)(19 << 20));                 // 32 MB (B,N,N) bf16

  prep_uv      <<<32, 256, 0, stream>>>(U, V, uvt);
  prep_x       <<<dim3(Nn / 64, Dd / 64, Bb), 256, 0, stream>>>(x, xt);
  proj_qk      <<<(Bb * Nn) / 16, 256, 0, stream>>>(x, mask, uvt, Qw, Kw);
  score_softmax<<<Bb * (Nn / 16), 512, 0, stream>>>(Qw, Kw, Pw, linv);
  pv_gemm      <<<Bb * (Nn / 128) * (Dd / 128), 256, 0, stream>>>(Pw, xt, x, linv, out);
  ln_k         <<<(Bb * Nn) / 4, 256, 0, stream>>>(out, gamma, beta);
}